// Round 8
// baseline (2209.294 us; speedup 1.0000x reference)
//
#include <hip/hip_runtime.h>

#define DD 8
#define SS 64
#define HH 128
#define OUTD 8
#define TT 2049
#define BB 32
#define WINW 16
#define NWIN 128
#define PP 28

typedef __attribute__((ext_vector_type(8))) short short8v;
typedef __attribute__((ext_vector_type(4))) float f32x4;

__device__ __forceinline__ float softplus_f(float x){
    return fmaxf(x, 0.f) + __logf(1.f + __expf(-fabsf(x)));
}
__device__ __forceinline__ float sigmoid_f(float x){
    return 1.f / (1.f + __expf(-x));
}
__device__ __forceinline__ float tanh_f(float x){
    float e = __expf(2.f * x);
    return 1.f - 2.f / (e + 1.f);
}
__device__ __forceinline__ unsigned short f2bf(float f){
    unsigned u = __builtin_bit_cast(unsigned, f);
    unsigned r = (u + 0x7FFFu + ((u >> 16) & 1u)) >> 16;
    return (unsigned short)r;
}
__device__ __forceinline__ unsigned pk2(float a, float b){
    return (unsigned)f2bf(a) | ((unsigned)f2bf(b) << 16);
}

// ---------------- signatures: s1 (B,NWIN,D), s2 (B,NWIN,P) ----------------
__global__ void sig_kernel(const float* __restrict__ x,
                           float* __restrict__ s1o, float* __restrict__ s2o){
    int w = blockIdx.x * blockDim.x + threadIdx.x;
    if (w >= BB * NWIN) return;
    int b = w >> 7, n = w & (NWIN - 1);
    const float* xp = x + ((size_t)b * TT + (size_t)n * WINW) * DD;
    float prev[DD], cum[DD], s1v[DD], M[DD][DD];
    #pragma unroll
    for (int i = 0; i < DD; ++i){
        cum[i] = 0.f; s1v[i] = 0.f;
        #pragma unroll
        for (int j = 0; j < DD; ++j) M[i][j] = 0.f;
    }
    #pragma unroll
    for (int i = 0; i < DD; ++i) prev[i] = xp[i];
    for (int t = 0; t < WINW; ++t){
        float cur[DD], del[DD];
        #pragma unroll
        for (int i = 0; i < DD; ++i) cur[i] = xp[(t + 1) * DD + i];
        #pragma unroll
        for (int i = 0; i < DD; ++i) del[i] = cur[i] - prev[i];
        #pragma unroll
        for (int i = 0; i < DD; ++i){
            #pragma unroll
            for (int j = 0; j < DD; ++j) M[i][j] += cum[i] * del[j];
        }
        #pragma unroll
        for (int i = 0; i < DD; ++i){ cum[i] += del[i]; s1v[i] += del[i]; prev[i] = cur[i]; }
    }
    #pragma unroll
    for (int i = 0; i < DD; ++i) s1o[(size_t)w * DD + i] = s1v[i];
    int p = 0;
    #pragma unroll
    for (int i = 0; i < DD; ++i){
        #pragma unroll
        for (int j = i + 1; j < DD; ++j){ s2o[(size_t)w * PP + p] = 0.5f * (M[i][j] - M[j][i]); ++p; }
    }
}

// image position (shorts): k-row k, col nn of a [K/32][64][8] B-image
#define BPOS(k, nn) ((((k) >> 5) * 64 + (((k) >> 3) & 3) * 16 + (nn)) * 8 + ((k) & 7))

// Cm row loader: row d of C matrix (8 coeffs) from s2g triangular storage
__device__ __forceinline__ void load_cm(const float* __restrict__ bco, int d, float* cm){
    #pragma unroll
    for (int e = 0; e < 8; ++e){
        if (e == d) cm[e] = 0.f;
        else if (e < d) cm[e] =  bco[((e * (15 - e)) >> 1) + d - e - 1];
        else            cm[e] = -bco[((d * (15 - d)) >> 1) + e - d - 1];
    }
}

// ---------------- main scan: 4 chains per block (2 pairs x 2 chains), 16 waves ----------------
__global__ __launch_bounds__(1024, 1) void scan_kernel(
    const float* __restrict__ x,
    const float* __restrict__ Wi0, const float* __restrict__ bi0,
    const float* __restrict__ Wi1, const float* __restrict__ bi1,
    const float* __restrict__ Wi2, const float* __restrict__ bi2,
    const float* __restrict__ Wv0, const float* __restrict__ bv0,
    const float* __restrict__ Wv1, const float* __restrict__ bv1,
    const float* __restrict__ Wv2, const float* __restrict__ bv2,
    const float* __restrict__ Wr,  const float* __restrict__ br,
    const float* __restrict__ s1g, const float* __restrict__ s2g,
    float* __restrict__ out)
{
    const int tid  = threadIdx.x;
    const int pair = tid >> 9;          // 0 or 1
    const int w    = (tid >> 6) & 7;    // wave within pair
    const int l    = tid & 63;
    const int lg   = l >> 4;
    const int ln   = l & 15;
    const int b0   = blockIdx.x * 4;
    const int chBase = b0 + 2 * pair;   // this pair's first chain

    __shared__ __align__(16) short BpH[2][2 * 64 * 8];
    __shared__ __align__(16) short Bp0[2][4 * 64 * 8];
    __shared__ __align__(16) short Bp1[2][4 * 64 * 8];
    __shared__ __align__(16) short BpV[2][2 * 64 * 8];
    __shared__ __align__(16) short Bp8[2][4 * 64 * 8];
    __shared__ __align__(16) short Bp9[2][4 * 64 * 8];
    __shared__ __align__(16) float s0p[2][2 * HH], s1p[2][2 * HH];
    __shared__ __align__(16) float Vl[2][1024], Rf[2][1024];
    __shared__ __align__(16) float hfb[2][2][2][SS];   // [pair][chain][buf][s]
    __shared__ __align__(16) float bv0L[HH], bv1L[HH], bv2L[512];
    __shared__ __align__(16) float WrL[OUTD * SS];
    __shared__ float brL[OUTD];

    // -------- prologue --------
    for (int i = tid; i < 2 * 2 * 64 * 8; i += 1024){ ((short*)BpH)[i] = 0; ((short*)BpV)[i] = 0; }
    for (int i = tid; i < 2 * 4 * 64 * 8; i += 1024){
        ((short*)Bp0)[i] = 0; ((short*)Bp1)[i] = 0; ((short*)Bp8)[i] = 0; ((short*)Bp9)[i] = 0;
    }

    // register-resident A-fragments (per wave; identical across pairs)
    short8v a0f[2], a1f[4];
    short8v a2f0[4], a2f1[4], a2f2[4], a2f3[4];
    #pragma unroll
    for (int ks = 0; ks < 2; ++ks){
        const float* p = Wv0 + (size_t)(w * 16 + ln) * SS + ks * 32 + lg * 8;
        short8v f;
        #pragma unroll
        for (int j = 0; j < 8; ++j) f[j] = (short)f2bf(p[j]);
        a0f[ks] = f;
    }
    #pragma unroll
    for (int ks = 0; ks < 4; ++ks){
        const float* p = Wv1 + (size_t)(w * 16 + ln) * HH + ks * 32 + lg * 8;
        short8v f;
        #pragma unroll
        for (int j = 0; j < 8; ++j) f[j] = (short)f2bf(p[j]);
        a1f[ks] = f;
    }
    #pragma unroll
    for (int ks = 0; ks < 4; ++ks){
        const float* p0 = Wv2 + (size_t)(64 * w + 0 * 16 + ln) * HH + ks * 32 + lg * 8;
        const float* p1 = Wv2 + (size_t)(64 * w + 1 * 16 + ln) * HH + ks * 32 + lg * 8;
        const float* p2 = Wv2 + (size_t)(64 * w + 2 * 16 + ln) * HH + ks * 32 + lg * 8;
        const float* p3 = Wv2 + (size_t)(64 * w + 3 * 16 + ln) * HH + ks * 32 + lg * 8;
        short8v f0, f1, f2, f3;
        #pragma unroll
        for (int j = 0; j < 8; ++j){
            f0[j] = (short)f2bf(p0[j]); f1[j] = (short)f2bf(p1[j]);
            f2[j] = (short)f2bf(p2[j]); f3[j] = (short)f2bf(p3[j]);
        }
        a2f0[ks] = f0; a2f1[ks] = f1; a2f2[ks] = f2; a2f3[ks] = f3;
    }
    if (tid < HH){ bv0L[tid] = bv0[tid]; bv1L[tid] = bv1[tid]; }
    if (tid < 512){ bv2L[tid] = bv2[tid]; WrL[tid] = Wr[tid]; }
    if (tid < OUTD) brL[tid] = br[tid];
    __syncthreads();

    // initial MLP (f32): 4 chains via tid<512 (L0/L1), tid<256 (L2)
    if (tid < 512){
        int c4 = tid >> 7, r = tid & 127;
        float acc = bi0[r];
        const float* x0 = x + (size_t)(b0 + c4) * TT * DD;
        #pragma unroll
        for (int k = 0; k < DD; ++k) acc += Wi0[r * DD + k] * x0[k];
        s0p[c4 >> 1][(c4 & 1) * HH + r] = softplus_f(acc);
    }
    __syncthreads();
    if (tid < 512){
        int c4 = tid >> 7, r = tid & 127;
        float acc = bi1[r];
        const f32x4* wv = (const f32x4*)(Wi1 + (size_t)r * HH);
        const f32x4* zv = (const f32x4*)&s0p[c4 >> 1][(c4 & 1) * HH];
        #pragma unroll 8
        for (int k = 0; k < 32; ++k){
            f32x4 a = wv[k], z = zv[k];
            acc += a.x * z.x + a.y * z.y + a.z * z.z + a.w * z.w;
        }
        s1p[c4 >> 1][(c4 & 1) * HH + r] = softplus_f(acc);
    }
    __syncthreads();
    if (tid < 256){
        int c4 = tid >> 6, s = tid & 63;
        float acc = bi2[s];
        const f32x4* wv = (const f32x4*)(Wi2 + (size_t)s * HH);
        const f32x4* zv = (const f32x4*)&s1p[c4 >> 1][(c4 & 1) * HH];
        #pragma unroll 8
        for (int k = 0; k < 32; ++k){
            f32x4 a = wv[k], z = zv[k];
            acc += a.x * z.x + a.y * z.y + a.z * z.z + a.w * z.w;
        }
        hfb[c4 >> 1][c4 & 1][0][s] = acc;
        BpH[c4 >> 1][BPOS(s, c4 & 1)] = (short)f2bf(acc);
    }

    // per-thread Cm row registers for step 0 (chain = chBase + (ln>>3), row d = ln&7)
    float cm[8];
    {
        const int cc = ln >> 3, d = ln & 7;
        load_cm(s2g + (size_t)(chBase + cc) * NWIN * PP, d, cm);
    }
    __syncthreads();

    const f32x4 zero4 = {0.f, 0.f, 0.f, 0.f};
    const int rb = w * 16 + lg * 4;
    short* BpH_p = BpH[pair]; short* Bp0_p = Bp0[pair]; short* Bp1_p = Bp1[pair];
    short* BpV_p = BpV[pair]; short* Bp8_p = Bp8[pair]; short* Bp9_p = Bp9[pair];
    float* s0p_p = s0p[pair]; float* s1p_p = s1p[pair];
    float* Vl_p = Vl[pair];   float* Rf_p = Rf[pair];
    float aReg = 0.f;

    // -------- scan --------
    for (int n = 0; n < NWIN; ++n){
        // ---- S1: z0 = sp(W0 @ h); also issue a-coeff load for upd(n) ----
        {
            if (w < 2 && l < 8) aReg = s1g[((size_t)(chBase + w) * NWIN + n) * DD + l];
            f32x4 acc = zero4;
            acc = __builtin_amdgcn_mfma_f32_16x16x32_bf16(a0f[0], *(const short8v*)&BpH_p[(0 * 64 + l) * 8], acc, 0, 0, 0);
            acc = __builtin_amdgcn_mfma_f32_16x16x32_bf16(a0f[1], *(const short8v*)&BpH_p[(1 * 64 + l) * 8], acc, 0, 0, 0);
            if (ln < 2){
                int c = ln;
                f32x4 bv = *(const f32x4*)&bv0L[rb];
                f32x4 sg; float z[4];
                #pragma unroll
                for (int r = 0; r < 4; ++r){
                    float p = acc[r] + bv[r];
                    z[r] = softplus_f(p); sg[r] = sigmoid_f(p);
                }
                *(f32x4*)&s0p_p[c * HH + rb] = sg;
                uint2 pk; pk.x = pk2(z[0], z[1]); pk.y = pk2(z[2], z[3]);
                *(uint2*)&Bp0_p[BPOS(rb, c)] = pk;
            }
        }
        __syncthreads();

        // ---- S3: z1 = sp(W1 @ z0); chain c -> Bp1 cols 4c..4c+3 (dup) ----
        {
            f32x4 acc = zero4;
            #pragma unroll
            for (int ks = 0; ks < 4; ++ks)
                acc = __builtin_amdgcn_mfma_f32_16x16x32_bf16(a1f[ks], *(const short8v*)&Bp0_p[(ks * 64 + l) * 8], acc, 0, 0, 0);
            if (ln < 2){
                int c = ln;
                f32x4 bv = *(const f32x4*)&bv1L[rb];
                f32x4 sg; float z[4];
                #pragma unroll
                for (int r = 0; r < 4; ++r){
                    float p = acc[r] + bv[r];
                    z[r] = softplus_f(p); sg[r] = sigmoid_f(p);
                }
                *(f32x4*)&s1p_p[c * HH + rb] = sg;
                uint2 pk; pk.x = pk2(z[0], z[1]); pk.y = pk2(z[2], z[3]);
                #pragma unroll
                for (int cc = 0; cc < 4; ++cc) *(uint2*)&Bp1_p[BPOS(rb, c * 4 + cc)] = pk;
            }
        }
        __syncthreads();

        // ---- S4: V_d = tanh(W2_d @ z1 + bv2), d = w ----
        {
            short8v bf[4];
            #pragma unroll
            for (int ks = 0; ks < 4; ++ks) bf[ks] = *(const short8v*)&Bp1_p[(ks * 64 + l) * 8];
            f32x4 acc0 = zero4, acc1 = zero4, acc2 = zero4, acc3 = zero4;
            #pragma unroll
            for (int ks = 0; ks < 4; ++ks){
                acc0 = __builtin_amdgcn_mfma_f32_16x16x32_bf16(a2f0[ks], bf[ks], acc0, 0, 0, 0);
                acc1 = __builtin_amdgcn_mfma_f32_16x16x32_bf16(a2f1[ks], bf[ks], acc1, 0, 0, 0);
                acc2 = __builtin_amdgcn_mfma_f32_16x16x32_bf16(a2f2[ks], bf[ks], acc2, 0, 0, 0);
                acc3 = __builtin_amdgcn_mfma_f32_16x16x32_bf16(a2f3[ks], bf[ks], acc3, 0, 0, 0);
            }
            if (ln < 8){
                int c = ln >> 2, t = ln & 3;
                f32x4 av = (t == 0) ? acc0 : (t == 1) ? acc1 : (t == 2) ? acc2 : acc3;
                int r4 = 64 * w + t * 16 + lg * 4;
                f32x4 bv = *(const f32x4*)&bv2L[r4];
                f32x4 vv;
                #pragma unroll
                for (int r = 0; r < 4; ++r) vv[r] = tanh_f(av[r] + bv[r]);
                *(f32x4*)&Vl_p[c * 512 + r4] = vv;
                int sl = t * 16 + lg * 4;
                uint2 pk; pk.x = pk2(vv[0], vv[1]); pk.y = pk2(vv[2], vv[3]);
                *(uint2*)&BpV_p[BPOS(sl, c * 8 + w)] = pk;
            }
        }
        __syncthreads();

        // ---- S7: Y = W0 @ V^T (N=16); t0 mix via cm registers ----
        {
            f32x4 acc = zero4;
            acc = __builtin_amdgcn_mfma_f32_16x16x32_bf16(a0f[0], *(const short8v*)&BpV_p[(0 * 64 + l) * 8], acc, 0, 0, 0);
            acc = __builtin_amdgcn_mfma_f32_16x16x32_bf16(a0f[1], *(const short8v*)&BpV_p[(1 * 64 + l) * 8], acc, 0, 0, 0);
            const int c = ln >> 3;
            float tm0 = 0.f, tm1 = 0.f, tm2 = 0.f, tm3 = 0.f;
            #pragma unroll
            for (int e = 0; e < 8; ++e){
                float ce = cm[e];
                int src = (l & 48) | (ln & 8) | e;
                tm0 += ce * __shfl(acc[0], src);
                tm1 += ce * __shfl(acc[1], src);
                tm2 += ce * __shfl(acc[2], src);
                tm3 += ce * __shfl(acc[3], src);
            }
            f32x4 sg = *(const f32x4*)&s0p_p[c * HH + rb];
            uint2 pk; pk.x = pk2(sg[0] * tm0, sg[1] * tm1); pk.y = pk2(sg[2] * tm2, sg[3] * tm3);
            *(uint2*)&Bp8_p[BPOS(rb, ln)] = pk;
        }
        __syncthreads();

        // ---- S8: q = s1' * (W1 @ t0); also prefetch cm for step n+1 ----
        {
            {
                int nn = (n + 1 < NWIN) ? n + 1 : n;
                const int cc = ln >> 3, d = ln & 7;
                load_cm(s2g + ((size_t)(chBase + cc) * NWIN + nn) * PP, d, cm);
            }
            f32x4 acc = zero4;
            #pragma unroll
            for (int ks = 0; ks < 4; ++ks)
                acc = __builtin_amdgcn_mfma_f32_16x16x32_bf16(a1f[ks], *(const short8v*)&Bp8_p[(ks * 64 + l) * 8], acc, 0, 0, 0);
            int c = ln >> 3;
            f32x4 sg = *(const f32x4*)&s1p_p[c * HH + rb];
            uint2 pk; pk.x = pk2(sg[0] * acc[0], sg[1] * acc[1]); pk.y = pk2(sg[2] * acc[2], sg[3] * acc[3]);
            *(uint2*)&Bp9_p[BPOS(rb, ln)] = pk;
        }
        __syncthreads();

        // ---- S9: R_d = (1-V_d^2) * (W2_d @ q[:,c,d]), d = w ----
        {
            short8v bf[4];
            #pragma unroll
            for (int ks = 0; ks < 4; ++ks) bf[ks] = *(const short8v*)&Bp9_p[(ks * 64 + l) * 8];
            f32x4 acc0 = zero4, acc1 = zero4, acc2 = zero4, acc3 = zero4;
            #pragma unroll
            for (int ks = 0; ks < 4; ++ks){
                acc0 = __builtin_amdgcn_mfma_f32_16x16x32_bf16(a2f0[ks], bf[ks], acc0, 0, 0, 0);
                acc1 = __builtin_amdgcn_mfma_f32_16x16x32_bf16(a2f1[ks], bf[ks], acc1, 0, 0, 0);
                acc2 = __builtin_amdgcn_mfma_f32_16x16x32_bf16(a2f2[ks], bf[ks], acc2, 0, 0, 0);
                acc3 = __builtin_amdgcn_mfma_f32_16x16x32_bf16(a2f3[ks], bf[ks], acc3, 0, 0, 0);
            }
            if ((ln & 7) == w){
                int c = ln >> 3;
                #pragma unroll
                for (int t = 0; t < 4; ++t){
                    f32x4 av = (t == 0) ? acc0 : (t == 1) ? acc1 : (t == 2) ? acc2 : acc3;
                    int r4 = 64 * w + t * 16 + lg * 4;
                    f32x4 vv = *(const f32x4*)&Vl_p[c * 512 + r4];
                    f32x4 rr;
                    #pragma unroll
                    for (int r = 0; r < 4; ++r) rr[r] = (1.f - vv[r] * vv[r]) * av[r];
                    *(f32x4*)&Rf_p[c * 512 + r4] = rr;
                }
            }
        }
        __syncthreads();

        // ---- upd: waves 0-1 h-update | waves 2-3 readout (direct global store) ----
        {
            const int cur = n & 1;
            if (w < 2){
                int cc = w, s = l;
                float hN = hfb[pair][cc][cur][s];
                #pragma unroll
                for (int d = 0; d < DD; ++d)
                    hN += __shfl(aReg, d) * Vl_p[cc * 512 + d * 64 + s] + Rf_p[cc * 512 + d * 64 + s];
                hfb[pair][cc][cur ^ 1][s] = hN;
                BpH_p[BPOS(s, cc)] = (short)f2bf(hN);
            } else if (w < 4){
                int cc = w - 2;
                int o = l >> 3, qq = l & 7;
                f32x4 w0 = *(const f32x4*)&WrL[o * SS + qq * 8];
                f32x4 w1 = *(const f32x4*)&WrL[o * SS + qq * 8 + 4];
                f32x4 h0 = *(const f32x4*)&hfb[pair][cc][cur][qq * 8];
                f32x4 h1 = *(const f32x4*)&hfb[pair][cc][cur][qq * 8 + 4];
                float acc = w0.x*h0.x + w0.y*h0.y + w0.z*h0.z + w0.w*h0.w
                          + w1.x*h1.x + w1.y*h1.y + w1.z*h1.z + w1.w*h1.w;
                acc += __shfl_xor(acc, 1); acc += __shfl_xor(acc, 2); acc += __shfl_xor(acc, 4);
                if (qq == 0)
                    out[(size_t)(chBase + cc) * (NWIN + 1) * OUTD + n * OUTD + o] = brL[o] + acc;
            }
        }
        __syncthreads();
    }

    // final readout: h_NWIN in hfb[pair][cc][0] (NWIN even)
    if (w == 2 || w == 3){
        int cc = w - 2;
        int o = l >> 3, qq = l & 7;
        f32x4 w0 = *(const f32x4*)&WrL[o * SS + qq * 8];
        f32x4 w1 = *(const f32x4*)&WrL[o * SS + qq * 8 + 4];
        f32x4 h0 = *(const f32x4*)&hfb[pair][cc][0][qq * 8];
        f32x4 h1 = *(const f32x4*)&hfb[pair][cc][0][qq * 8 + 4];
        float acc = w0.x*h0.x + w0.y*h0.y + w0.z*h0.z + w0.w*h0.w
                  + w1.x*h1.x + w1.y*h1.y + w1.z*h1.z + w1.w*h1.w;
        acc += __shfl_xor(acc, 1); acc += __shfl_xor(acc, 2); acc += __shfl_xor(acc, 4);
        if (qq == 0)
            out[(size_t)(chBase + cc) * (NWIN + 1) * OUTD + NWIN * OUTD + o] = brL[o] + acc;
    }
}

extern "C" void kernel_launch(void* const* d_in, const int* in_sizes, int n_in,
                              void* d_out, int out_size, void* d_ws, size_t ws_size,
                              hipStream_t stream){
    const float* x   = (const float*)d_in[1];
    const float* Wi0 = (const float*)d_in[2];
    const float* bi0 = (const float*)d_in[3];
    const float* Wi1 = (const float*)d_in[4];
    const float* bi1 = (const float*)d_in[5];
    const float* Wi2 = (const float*)d_in[6];
    const float* bi2 = (const float*)d_in[7];
    const float* Wv0 = (const float*)d_in[8];
    const float* bv0 = (const float*)d_in[9];
    const float* Wv1 = (const float*)d_in[10];
    const float* bv1 = (const float*)d_in[11];
    const float* Wv2 = (const float*)d_in[12];
    const float* bv2 = (const float*)d_in[13];
    const float* Wr  = (const float*)d_in[14];
    const float* br  = (const float*)d_in[15];
    float* out = (float*)d_out;

    float* s1w = (float*)d_ws;
    float* s2w = s1w + (size_t)BB * NWIN * DD;

    sig_kernel<<<(BB * NWIN + 255) / 256, 256, 0, stream>>>(x, s1w, s2w);
    scan_kernel<<<BB / 4, 1024, 0, stream>>>(x, Wi0, bi0, Wi1, bi1, Wi2, bi2,
                                             Wv0, bv0, Wv1, bv1, Wv2, bv2,
                                             Wr, br, s1w, s2w, out);
}

// Round 9
// 802.138 us; speedup vs baseline: 2.7543x; 2.7543x over previous
//
#include <hip/hip_runtime.h>

#define DD 8
#define SS 64
#define HH 128
#define OUTD 8
#define TT 2049
#define BB 32
#define WINW 16
#define NWIN 128
#define PP 28

typedef __attribute__((ext_vector_type(8))) short short8v;
typedef __attribute__((ext_vector_type(4))) float f32x4;

__device__ __forceinline__ float softplus_f(float x){
    return fmaxf(x, 0.f) + __logf(1.f + __expf(-fabsf(x)));
}
__device__ __forceinline__ float sigmoid_f(float x){
    return 1.f / (1.f + __expf(-x));
}
__device__ __forceinline__ float tanh_f(float x){
    float e = __expf(2.f * x);
    return 1.f - 2.f / (e + 1.f);
}
__device__ __forceinline__ unsigned short f2bf(float f){
    unsigned u = __builtin_bit_cast(unsigned, f);
    unsigned r = (u + 0x7FFFu + ((u >> 16) & 1u)) >> 16;
    return (unsigned short)r;
}
__device__ __forceinline__ unsigned pk2(float a, float b){
    return (unsigned)f2bf(a) | ((unsigned)f2bf(b) << 16);
}

// ---------------- signatures: s1 (B,NWIN,D), s2 (B,NWIN,P) ----------------
__global__ void sig_kernel(const float* __restrict__ x,
                           float* __restrict__ s1o, float* __restrict__ s2o){
    int w = blockIdx.x * blockDim.x + threadIdx.x;
    if (w >= BB * NWIN) return;
    int b = w >> 7, n = w & (NWIN - 1);
    const float* xp = x + ((size_t)b * TT + (size_t)n * WINW) * DD;
    float prev[DD], cum[DD], s1v[DD], M[DD][DD];
    #pragma unroll
    for (int i = 0; i < DD; ++i){
        cum[i] = 0.f; s1v[i] = 0.f;
        #pragma unroll
        for (int j = 0; j < DD; ++j) M[i][j] = 0.f;
    }
    #pragma unroll
    for (int i = 0; i < DD; ++i) prev[i] = xp[i];
    for (int t = 0; t < WINW; ++t){
        float cur[DD], del[DD];
        #pragma unroll
        for (int i = 0; i < DD; ++i) cur[i] = xp[(t + 1) * DD + i];
        #pragma unroll
        for (int i = 0; i < DD; ++i) del[i] = cur[i] - prev[i];
        #pragma unroll
        for (int i = 0; i < DD; ++i){
            #pragma unroll
            for (int j = 0; j < DD; ++j) M[i][j] += cum[i] * del[j];
        }
        #pragma unroll
        for (int i = 0; i < DD; ++i){ cum[i] += del[i]; s1v[i] += del[i]; prev[i] = cur[i]; }
    }
    #pragma unroll
    for (int i = 0; i < DD; ++i) s1o[(size_t)w * DD + i] = s1v[i];
    int p = 0;
    #pragma unroll
    for (int i = 0; i < DD; ++i){
        #pragma unroll
        for (int j = i + 1; j < DD; ++j){ s2o[(size_t)w * PP + p] = 0.5f * (M[i][j] - M[j][i]); ++p; }
    }
}

// image position (shorts): k-row k, col nn of a [K/32][64][8] B-image
#define BPOS(k, nn) ((((k) >> 5) * 64 + (((k) >> 3) & 3) * 16 + (nn)) * 8 + ((k) & 7))

// Cm row loader from LDS triangular storage (one read + sign select per e)
__device__ __forceinline__ void load_cm_lds(const float* bco, int d, float* cm){
    #pragma unroll
    for (int e = 0; e < 8; ++e){
        int m = d < e ? d : e, M = d < e ? e : d;
        int idx = ((m * (15 - m)) >> 1) + M - m - 1;
        idx = idx < 0 ? 0 : idx;
        float v = bco[idx];
        cm[e] = (e == d) ? 0.f : (e < d ? v : -v);
    }
}

// ---------------- main scan: 4 chains per 512-thread block, 8 waves ----------------
__global__ __launch_bounds__(512, 2) void scan_kernel(
    const float* __restrict__ x,
    const float* __restrict__ Wi0, const float* __restrict__ bi0,
    const float* __restrict__ Wi1, const float* __restrict__ bi1,
    const float* __restrict__ Wi2, const float* __restrict__ bi2,
    const float* __restrict__ Wv0, const float* __restrict__ bv0,
    const float* __restrict__ Wv1, const float* __restrict__ bv1,
    const float* __restrict__ Wv2, const float* __restrict__ bv2,
    const float* __restrict__ Wr,  const float* __restrict__ br,
    const float* __restrict__ s1g, const float* __restrict__ s2g,
    float* __restrict__ out)
{
    const int tid = threadIdx.x;
    const int w   = tid >> 6;   // wave 0..7 (= m-tile / d-block)
    const int l   = tid & 63;
    const int lg  = l >> 4;
    const int ln  = l & 15;
    const int b0  = blockIdx.x * 4;

    // B-images: GEMV stages share one image (4 chains in cols); tangent stages per pair
    __shared__ __align__(16) short BpH[2 * 64 * 8];       // h:  cols 0-3 = chains
    __shared__ __align__(16) short Bp0[4 * 64 * 8];       // z0: cols 0-3
    __shared__ __align__(16) short Bp1[4 * 64 * 8];       // z1: chain c -> cols 4c..4c+3 (dup)
    __shared__ __align__(16) short BpV[2][2 * 64 * 8];    // V:  pair p, col (c&1)*8+d
    __shared__ __align__(16) short Bp8[2][4 * 64 * 8];    // t0
    __shared__ __align__(16) short Bp9[2][4 * 64 * 8];    // q
    __shared__ __align__(16) float s0p[4][HH], s1p[4][HH];
    __shared__ __align__(16) float Vl[4 * 512], Rf[4 * 512];
    __shared__ __align__(16) float hfb[4][2][SS];
    __shared__ __align__(16) float bv0L[HH], bv1L[HH], bv2L[512];
    __shared__ __align__(16) float WrL[OUTD * SS];
    __shared__ float brL[OUTD];
    __shared__ __align__(16) float sAll[4][NWIN * DD];    // 16 KB
    __shared__ __align__(16) float bAll[4][NWIN * PP];    // 56 KB
    __shared__ __align__(16) float outC[4][32][OUTD];     // 4 KB output chunk

    // -------- prologue: reg A-fragments, stage weights + coefficients --------
    short8v a0f[2], a1f[4];
    short8v a2f0[4], a2f1[4], a2f2[4], a2f3[4];
    #pragma unroll
    for (int ks = 0; ks < 2; ++ks){
        const float* p = Wv0 + (size_t)(w * 16 + ln) * SS + ks * 32 + lg * 8;
        short8v f;
        #pragma unroll
        for (int j = 0; j < 8; ++j) f[j] = (short)f2bf(p[j]);
        a0f[ks] = f;
    }
    #pragma unroll
    for (int ks = 0; ks < 4; ++ks){
        const float* p = Wv1 + (size_t)(w * 16 + ln) * HH + ks * 32 + lg * 8;
        short8v f;
        #pragma unroll
        for (int j = 0; j < 8; ++j) f[j] = (short)f2bf(p[j]);
        a1f[ks] = f;
    }
    #pragma unroll
    for (int ks = 0; ks < 4; ++ks){
        const float* p0 = Wv2 + (size_t)(64 * w + 0 * 16 + ln) * HH + ks * 32 + lg * 8;
        const float* p1 = Wv2 + (size_t)(64 * w + 1 * 16 + ln) * HH + ks * 32 + lg * 8;
        const float* p2 = Wv2 + (size_t)(64 * w + 2 * 16 + ln) * HH + ks * 32 + lg * 8;
        const float* p3 = Wv2 + (size_t)(64 * w + 3 * 16 + ln) * HH + ks * 32 + lg * 8;
        short8v f0, f1, f2, f3;
        #pragma unroll
        for (int j = 0; j < 8; ++j){
            f0[j] = (short)f2bf(p0[j]); f1[j] = (short)f2bf(p1[j]);
            f2[j] = (short)f2bf(p2[j]); f3[j] = (short)f2bf(p3[j]);
        }
        a2f0[ks] = f0; a2f1[ks] = f1; a2f2[ks] = f2; a2f3[ks] = f3;
    }
    if (tid < HH){ bv0L[tid] = bv0[tid]; bv1L[tid] = bv1[tid]; }
    bv2L[tid] = bv2[tid];
    WrL[tid]  = Wr[tid];
    if (tid < OUTD) brL[tid] = br[tid];
    {
        float* sF = &sAll[0][0];
        for (int i = tid; i < 4 * NWIN * DD; i += 512){
            int c = i >> 10;
            sF[i] = s1g[(size_t)(b0 + c) * (NWIN * DD) + (i & 1023)];
        }
        float* bF = &bAll[0][0];
        for (int i = tid; i < 4 * NWIN * PP; i += 512){
            int c = i / (NWIN * PP);
            bF[i] = s2g[(size_t)(b0 + c) * (NWIN * PP) + (i - c * (NWIN * PP))];
        }
    }
    __syncthreads();

    // -------- initial MLP (f32) for 4 chains; s0p/s1p as scratch --------
    {
        int c4 = tid >> 7, r = tid & 127;
        float acc = bi0[r];
        const float* x0 = x + (size_t)(b0 + c4) * TT * DD;
        #pragma unroll
        for (int k = 0; k < DD; ++k) acc += Wi0[r * DD + k] * x0[k];
        s0p[c4][r] = softplus_f(acc);
    }
    __syncthreads();
    {
        int c4 = tid >> 7, r = tid & 127;
        float acc = bi1[r];
        const f32x4* wv = (const f32x4*)(Wi1 + (size_t)r * HH);
        const f32x4* zv = (const f32x4*)&s0p[c4][0];
        #pragma unroll 8
        for (int k = 0; k < 32; ++k){
            f32x4 a = wv[k], z = zv[k];
            acc += a.x * z.x + a.y * z.y + a.z * z.z + a.w * z.w;
        }
        s1p[c4][r] = softplus_f(acc);
    }
    __syncthreads();
    if (tid < 256){
        int c4 = tid >> 6, s = tid & 63;
        float acc = bi2[s];
        const f32x4* wv = (const f32x4*)(Wi2 + (size_t)s * HH);
        const f32x4* zv = (const f32x4*)&s1p[c4][0];
        #pragma unroll 8
        for (int k = 0; k < 32; ++k){
            f32x4 a = wv[k], z = zv[k];
            acc += a.x * z.x + a.y * z.y + a.z * z.z + a.w * z.w;
        }
        hfb[c4][0][s] = acc;
        BpH[BPOS(s, c4)] = (short)f2bf(acc);
    }
    __syncthreads();

    // per-thread Cm rows for step 0: cmA = chain (ln>>3), cmB = chain 2+(ln>>3), row d=ln&7
    float cmA[8], cmB[8];
    load_cm_lds(&bAll[ln >> 3][0], ln & 7, cmA);
    load_cm_lds(&bAll[2 + (ln >> 3)][0], ln & 7, cmB);

    const f32x4 zero4 = {0.f, 0.f, 0.f, 0.f};
    const int rb = w * 16 + lg * 4;

    // -------- scan --------
    for (int n = 0; n < NWIN; ++n){
        // ---- S1: z0 = sp(W0 @ h), cols 0-3 = 4 chains ----
        {
            f32x4 acc = zero4;
            acc = __builtin_amdgcn_mfma_f32_16x16x32_bf16(a0f[0], *(const short8v*)&BpH[(0 * 64 + l) * 8], acc, 0, 0, 0);
            acc = __builtin_amdgcn_mfma_f32_16x16x32_bf16(a0f[1], *(const short8v*)&BpH[(1 * 64 + l) * 8], acc, 0, 0, 0);
            if (ln < 4){
                int c = ln;
                f32x4 bv = *(const f32x4*)&bv0L[rb];
                f32x4 sg; float z[4];
                #pragma unroll
                for (int r = 0; r < 4; ++r){
                    float p = acc[r] + bv[r];
                    z[r] = softplus_f(p); sg[r] = sigmoid_f(p);
                }
                *(f32x4*)&s0p[c][rb] = sg;
                uint2 pk; pk.x = pk2(z[0], z[1]); pk.y = pk2(z[2], z[3]);
                *(uint2*)&Bp0[BPOS(rb, c)] = pk;
            }
        }
        __syncthreads();

        // ---- S3: z1 = sp(W1 @ z0); chain c -> Bp1 cols 4c..4c+3 (dup) ----
        {
            f32x4 acc = zero4;
            #pragma unroll
            for (int ks = 0; ks < 4; ++ks)
                acc = __builtin_amdgcn_mfma_f32_16x16x32_bf16(a1f[ks], *(const short8v*)&Bp0[(ks * 64 + l) * 8], acc, 0, 0, 0);
            if (ln < 4){
                int c = ln;
                f32x4 bv = *(const f32x4*)&bv1L[rb];
                f32x4 sg; float z[4];
                #pragma unroll
                for (int r = 0; r < 4; ++r){
                    float p = acc[r] + bv[r];
                    z[r] = softplus_f(p); sg[r] = sigmoid_f(p);
                }
                *(f32x4*)&s1p[c][rb] = sg;
                uint2 pk; pk.x = pk2(z[0], z[1]); pk.y = pk2(z[2], z[3]);
                #pragma unroll
                for (int cc = 0; cc < 4; ++cc) *(uint2*)&Bp1[BPOS(rb, c * 4 + cc)] = pk;
            }
        }
        __syncthreads();

        // ---- S4: V_d = tanh(W2_d @ z1 + bv2), d = w; all 16 lanes: c=ln>>2, t=ln&3 ----
        {
            short8v bf[4];
            #pragma unroll
            for (int ks = 0; ks < 4; ++ks) bf[ks] = *(const short8v*)&Bp1[(ks * 64 + l) * 8];
            f32x4 acc0 = zero4, acc1 = zero4, acc2 = zero4, acc3 = zero4;
            #pragma unroll
            for (int ks = 0; ks < 4; ++ks){
                acc0 = __builtin_amdgcn_mfma_f32_16x16x32_bf16(a2f0[ks], bf[ks], acc0, 0, 0, 0);
                acc1 = __builtin_amdgcn_mfma_f32_16x16x32_bf16(a2f1[ks], bf[ks], acc1, 0, 0, 0);
                acc2 = __builtin_amdgcn_mfma_f32_16x16x32_bf16(a2f2[ks], bf[ks], acc2, 0, 0, 0);
                acc3 = __builtin_amdgcn_mfma_f32_16x16x32_bf16(a2f3[ks], bf[ks], acc3, 0, 0, 0);
            }
            {
                int c = ln >> 2, t = ln & 3;
                f32x4 av = (t == 0) ? acc0 : (t == 1) ? acc1 : (t == 2) ? acc2 : acc3;
                int r4 = 64 * w + t * 16 + lg * 4;
                f32x4 bv = *(const f32x4*)&bv2L[r4];
                f32x4 vv;
                #pragma unroll
                for (int r = 0; r < 4; ++r) vv[r] = tanh_f(av[r] + bv[r]);
                *(f32x4*)&Vl[c * 512 + r4] = vv;
                int sl = t * 16 + lg * 4;
                uint2 pk; pk.x = pk2(vv[0], vv[1]); pk.y = pk2(vv[2], vv[3]);
                *(uint2*)&BpV[c >> 1][BPOS(sl, (c & 1) * 8 + w)] = pk;
            }
        }
        __syncthreads();

        // ---- S7: per pair, Y = W0 @ V^T (N=16); t0 mix via cm regs ----
        {
            #pragma unroll
            for (int p = 0; p < 2; ++p){
                f32x4 acc = zero4;
                acc = __builtin_amdgcn_mfma_f32_16x16x32_bf16(a0f[0], *(const short8v*)&BpV[p][(0 * 64 + l) * 8], acc, 0, 0, 0);
                acc = __builtin_amdgcn_mfma_f32_16x16x32_bf16(a0f[1], *(const short8v*)&BpV[p][(1 * 64 + l) * 8], acc, 0, 0, 0);
                float tm0 = 0.f, tm1 = 0.f, tm2 = 0.f, tm3 = 0.f;
                #pragma unroll
                for (int e = 0; e < 8; ++e){
                    float ce = p ? cmB[e] : cmA[e];
                    int src = (l & 48) | (ln & 8) | e;
                    tm0 += ce * __shfl(acc[0], src);
                    tm1 += ce * __shfl(acc[1], src);
                    tm2 += ce * __shfl(acc[2], src);
                    tm3 += ce * __shfl(acc[3], src);
                }
                int c = 2 * p + (ln >> 3);
                f32x4 sg = *(const f32x4*)&s0p[c][rb];
                uint2 pk; pk.x = pk2(sg[0] * tm0, sg[1] * tm1); pk.y = pk2(sg[2] * tm2, sg[3] * tm3);
                *(uint2*)&Bp8[p][BPOS(rb, ln)] = pk;
            }
        }
        __syncthreads();

        // ---- S8: per pair, q = s1' * (W1 @ t0); prefetch cm for n+1 (LDS reads) ----
        {
            {
                int nn = (n + 1 < NWIN) ? n + 1 : n;
                load_cm_lds(&bAll[ln >> 3][nn * PP], ln & 7, cmA);
                load_cm_lds(&bAll[2 + (ln >> 3)][nn * PP], ln & 7, cmB);
            }
            #pragma unroll
            for (int p = 0; p < 2; ++p){
                f32x4 acc = zero4;
                #pragma unroll
                for (int ks = 0; ks < 4; ++ks)
                    acc = __builtin_amdgcn_mfma_f32_16x16x32_bf16(a1f[ks], *(const short8v*)&Bp8[p][(ks * 64 + l) * 8], acc, 0, 0, 0);
                int c = 2 * p + (ln >> 3);
                f32x4 sg = *(const f32x4*)&s1p[c][rb];
                uint2 pk; pk.x = pk2(sg[0] * acc[0], sg[1] * acc[1]); pk.y = pk2(sg[2] * acc[2], sg[3] * acc[3]);
                *(uint2*)&Bp9[p][BPOS(rb, ln)] = pk;
            }
        }
        __syncthreads();

        // ---- S9: per pair, R_d = (1-V_d^2) * (W2_d @ q[:,c,d]), d = w ----
        {
            #pragma unroll
            for (int p = 0; p < 2; ++p){
                short8v bf[4];
                #pragma unroll
                for (int ks = 0; ks < 4; ++ks) bf[ks] = *(const short8v*)&Bp9[p][(ks * 64 + l) * 8];
                f32x4 acc0 = zero4, acc1 = zero4, acc2 = zero4, acc3 = zero4;
                #pragma unroll
                for (int ks = 0; ks < 4; ++ks){
                    acc0 = __builtin_amdgcn_mfma_f32_16x16x32_bf16(a2f0[ks], bf[ks], acc0, 0, 0, 0);
                    acc1 = __builtin_amdgcn_mfma_f32_16x16x32_bf16(a2f1[ks], bf[ks], acc1, 0, 0, 0);
                    acc2 = __builtin_amdgcn_mfma_f32_16x16x32_bf16(a2f2[ks], bf[ks], acc2, 0, 0, 0);
                    acc3 = __builtin_amdgcn_mfma_f32_16x16x32_bf16(a2f3[ks], bf[ks], acc3, 0, 0, 0);
                }
                if ((ln & 7) == w){
                    int c = 2 * p + (ln >> 3);
                    #pragma unroll
                    for (int t = 0; t < 4; ++t){
                        f32x4 av = (t == 0) ? acc0 : (t == 1) ? acc1 : (t == 2) ? acc2 : acc3;
                        int r4 = 64 * w + t * 16 + lg * 4;
                        f32x4 vv = *(const f32x4*)&Vl[c * 512 + r4];
                        f32x4 rr;
                        #pragma unroll
                        for (int r = 0; r < 4; ++r) rr[r] = (1.f - vv[r] * vv[r]) * av[r];
                        *(f32x4*)&Rf[c * 512 + r4] = rr;
                    }
                }
            }
        }
        __syncthreads();

        // ---- upd: waves 0-3 h-update (c=w) | waves 4-7 readout (c=w-4) + chunk flush ----
        {
            const int cur = n & 1;
            if (w < 4){
                int c = w, s = l;
                float hN = hfb[c][cur][s];
                #pragma unroll
                for (int d = 0; d < DD; ++d)
                    hN += sAll[c][n * DD + d] * Vl[c * 512 + d * 64 + s] + Rf[c * 512 + d * 64 + s];
                hfb[c][cur ^ 1][s] = hN;
                BpH[BPOS(s, c)] = (short)f2bf(hN);
            } else {
                int c = w - 4;
                int o = l >> 3, qq = l & 7;
                f32x4 w0 = *(const f32x4*)&WrL[o * SS + qq * 8];
                f32x4 w1 = *(const f32x4*)&WrL[o * SS + qq * 8 + 4];
                f32x4 h0 = *(const f32x4*)&hfb[c][cur][qq * 8];
                f32x4 h1 = *(const f32x4*)&hfb[c][cur][qq * 8 + 4];
                float acc = w0.x*h0.x + w0.y*h0.y + w0.z*h0.z + w0.w*h0.w
                          + w1.x*h1.x + w1.y*h1.y + w1.z*h1.z + w1.w*h1.w;
                acc += __shfl_xor(acc, 1); acc += __shfl_xor(acc, 2); acc += __shfl_xor(acc, 4);
                if (qq == 0) outC[c][n & 31][o] = brL[o] + acc;
                if ((n & 31) == 31){
                    // flush 32-step chunk (wave-internal LDS write->read, program order)
                    size_t base = (size_t)(b0 + c) * (NWIN + 1) * OUTD + (size_t)(n - 31) * OUTD;
                    const f32x4* oc = (const f32x4*)&outC[c][0][0];
                    f32x4 v = oc[l];
                    *(f32x4*)&out[base + l * 4] = v;
                }
            }
        }
        __syncthreads();
    }

    // final readout: h_NWIN in hfb[c][0] (NWIN even)
    if (w >= 4){
        int c = w - 4;
        int o = l >> 3, qq = l & 7;
        f32x4 w0 = *(const f32x4*)&WrL[o * SS + qq * 8];
        f32x4 w1 = *(const f32x4*)&WrL[o * SS + qq * 8 + 4];
        f32x4 h0 = *(const f32x4*)&hfb[c][0][qq * 8];
        f32x4 h1 = *(const f32x4*)&hfb[c][0][qq * 8 + 4];
        float acc = w0.x*h0.x + w0.y*h0.y + w0.z*h0.z + w0.w*h0.w
                  + w1.x*h1.x + w1.y*h1.y + w1.z*h1.z + w1.w*h1.w;
        acc += __shfl_xor(acc, 1); acc += __shfl_xor(acc, 2); acc += __shfl_xor(acc, 4);
        if (qq == 0)
            out[(size_t)(b0 + c) * (NWIN + 1) * OUTD + (size_t)NWIN * OUTD + o] = brL[o] + acc;
    }
}

extern "C" void kernel_launch(void* const* d_in, const int* in_sizes, int n_in,
                              void* d_out, int out_size, void* d_ws, size_t ws_size,
                              hipStream_t stream){
    const float* x   = (const float*)d_in[1];
    const float* Wi0 = (const float*)d_in[2];
    const float* bi0 = (const float*)d_in[3];
    const float* Wi1 = (const float*)d_in[4];
    const float* bi1 = (const float*)d_in[5];
    const float* Wi2 = (const float*)d_in[6];
    const float* bi2 = (const float*)d_in[7];
    const float* Wv0 = (const float*)d_in[8];
    const float* bv0 = (const float*)d_in[9];
    const float* Wv1 = (const float*)d_in[10];
    const float* bv1 = (const float*)d_in[11];
    const float* Wv2 = (const float*)d_in[12];
    const float* bv2 = (const float*)d_in[13];
    const float* Wr  = (const float*)d_in[14];
    const float* br  = (const float*)d_in[15];
    float* out = (float*)d_out;

    float* s1w = (float*)d_ws;
    float* s2w = s1w + (size_t)BB * NWIN * DD;

    sig_kernel<<<(BB * NWIN + 255) / 256, 256, 0, stream>>>(x, s1w, s2w);
    scan_kernel<<<BB / 4, 512, 0, stream>>>(x, Wi0, bi0, Wi1, bi1, Wi2, bi2,
                                            Wv0, bv0, Wv1, bv1, Wv2, bv2,
                                            Wr, br, s1w, s2w, out);
}

// Round 11
// 663.501 us; speedup vs baseline: 3.3298x; 1.2089x over previous
//
#include <hip/hip_runtime.h>
#include <hip/hip_bf16.h>

#define DD 8
#define SS 64
#define HH 128
#define OUTD 8
#define TT 2049
#define BB 32
#define WINW 16
#define NWIN 128
#define PP 28

typedef __attribute__((ext_vector_type(8))) short short8v;
typedef __attribute__((ext_vector_type(4))) float f32x4;

__device__ __forceinline__ float softplus_f(float x){
    return fmaxf(x, 0.f) + __logf(1.f + __expf(-fabsf(x)));
}
__device__ __forceinline__ float tanh_f(float x){
    float e = __expf(2.f * x);
    return 1.f - 2.f / (e + 1.f);
}
// fused softplus + sigmoid sharing t = exp(-|x|)
__device__ __forceinline__ void sp_sig(float x, float& sp, float& sg){
    float t = __expf(-fabsf(x));
    float r = 1.f / (1.f + t);
    sg = x > 0.f ? r : 1.f - r;
    sp = fmaxf(x, 0.f) - __logf(r);
}
__device__ __forceinline__ unsigned short f2bf(float f){
    return __builtin_bit_cast(unsigned short, __float2bfloat16(f));
}
__device__ __forceinline__ unsigned pk2(float a, float b){
    unsigned lo = (unsigned)__builtin_bit_cast(unsigned short, __float2bfloat16(a));
    unsigned hi = (unsigned)__builtin_bit_cast(unsigned short, __float2bfloat16(b));
    return lo | (hi << 16);
}

// ---------------- signatures: s1 (B,NWIN,D), s2 (B,NWIN,P) ----------------
__global__ void sig_kernel(const float* __restrict__ x,
                           float* __restrict__ s1o, float* __restrict__ s2o){
    int w = blockIdx.x * blockDim.x + threadIdx.x;
    if (w >= BB * NWIN) return;
    int b = w >> 7, n = w & (NWIN - 1);
    const float* xp = x + ((size_t)b * TT + (size_t)n * WINW) * DD;
    float prev[DD], cum[DD], s1v[DD], M[DD][DD];
    #pragma unroll
    for (int i = 0; i < DD; ++i){
        cum[i] = 0.f; s1v[i] = 0.f;
        #pragma unroll
        for (int j = 0; j < DD; ++j) M[i][j] = 0.f;
    }
    #pragma unroll
    for (int i = 0; i < DD; ++i) prev[i] = xp[i];
    for (int t = 0; t < WINW; ++t){
        float cur[DD], del[DD];
        #pragma unroll
        for (int i = 0; i < DD; ++i) cur[i] = xp[(t + 1) * DD + i];
        #pragma unroll
        for (int i = 0; i < DD; ++i) del[i] = cur[i] - prev[i];
        #pragma unroll
        for (int i = 0; i < DD; ++i){
            #pragma unroll
            for (int j = 0; j < DD; ++j) M[i][j] += cum[i] * del[j];
        }
        #pragma unroll
        for (int i = 0; i < DD; ++i){ cum[i] += del[i]; s1v[i] += del[i]; prev[i] = cur[i]; }
    }
    #pragma unroll
    for (int i = 0; i < DD; ++i) s1o[(size_t)w * DD + i] = s1v[i];
    int p = 0;
    #pragma unroll
    for (int i = 0; i < DD; ++i){
        #pragma unroll
        for (int j = i + 1; j < DD; ++j){ s2o[(size_t)w * PP + p] = 0.5f * (M[i][j] - M[j][i]); ++p; }
    }
}

// image position (shorts): k-row k, col nn of a [K/32][64][8] B-image
#define BPOS(k, nn) ((((k) >> 5) * 64 + (((k) >> 3) & 3) * 16 + (nn)) * 8 + ((k) & 7))

// ---------------- main scan: 4 chains per 512-thread block, 8 waves ----------------
__global__ __launch_bounds__(512, 2) void scan_kernel(
    const float* __restrict__ x,
    const float* __restrict__ Wi0, const float* __restrict__ bi0,
    const float* __restrict__ Wi1, const float* __restrict__ bi1,
    const float* __restrict__ Wi2, const float* __restrict__ bi2,
    const float* __restrict__ Wv0, const float* __restrict__ bv0,
    const float* __restrict__ Wv1, const float* __restrict__ bv1,
    const float* __restrict__ Wv2, const float* __restrict__ bv2,
    const float* __restrict__ Wr,  const float* __restrict__ br,
    const float* __restrict__ s1g, const float* __restrict__ s2g,
    float* __restrict__ out)
{
    const int tid = threadIdx.x;
    const int w   = tid >> 6;   // wave 0..7 (= m-tile / d-block)
    const int l   = tid & 63;
    const int lg  = l >> 4;
    const int ln  = l & 15;
    const int b0  = blockIdx.x * 4;

    __shared__ __align__(16) short BpH[2 * 64 * 8];       // h:  cols 0-3 = chains
    __shared__ __align__(16) short Bp0[4 * 64 * 8];       // z0: cols 0-3
    __shared__ __align__(16) short Bp1[4 * 64 * 8];       // z1: chain c -> cols 4c..4c+3 (dup)
    __shared__ __align__(16) short BpV[2][2 * 64 * 8];    // V:  pair p, col (c&1)*8+d
    __shared__ __align__(16) short Bp8[2][4 * 64 * 8];    // t0
    __shared__ __align__(16) short Bp9[2][4 * 64 * 8];    // q
    __shared__ __align__(16) float s0p[4][HH], s1p[4][HH];
    __shared__ __align__(16) float Vl[4 * 512], Rf[4 * 512];
    __shared__ __align__(16) float hfb[4][2][SS];
    __shared__ __align__(16) float bv0L[HH], bv1L[HH], bv2L[512];
    __shared__ __align__(16) float WrL[OUTD * SS];
    __shared__ float brL[OUTD];
    __shared__ __align__(16) float sAll[4][NWIN * DD];    // 16 KB
    __shared__ __align__(16) float bAll[4][NWIN * PP];    // 56 KB
    __shared__ __align__(16) float outC[4][32][OUTD];     // 4 KB output chunk
    __shared__ __align__(16) float Cexp[4][DD][12];       // expanded C, padded rows (48B)

    // -------- prologue: reg A-fragments, stage weights + coefficients --------
    short8v a0f[2], a1f[4];
    short8v a2f0[4], a2f1[4], a2f2[4], a2f3[4];
    #pragma unroll
    for (int ks = 0; ks < 2; ++ks){
        const float* p = Wv0 + (size_t)(w * 16 + ln) * SS + ks * 32 + lg * 8;
        short8v f;
        #pragma unroll
        for (int j = 0; j < 8; ++j) f[j] = (short)f2bf(p[j]);
        a0f[ks] = f;
    }
    #pragma unroll
    for (int ks = 0; ks < 4; ++ks){
        const float* p = Wv1 + (size_t)(w * 16 + ln) * HH + ks * 32 + lg * 8;
        short8v f;
        #pragma unroll
        for (int j = 0; j < 8; ++j) f[j] = (short)f2bf(p[j]);
        a1f[ks] = f;
    }
    #pragma unroll
    for (int ks = 0; ks < 4; ++ks){
        const float* p0 = Wv2 + (size_t)(64 * w + 0 * 16 + ln) * HH + ks * 32 + lg * 8;
        const float* p1 = Wv2 + (size_t)(64 * w + 1 * 16 + ln) * HH + ks * 32 + lg * 8;
        const float* p2 = Wv2 + (size_t)(64 * w + 2 * 16 + ln) * HH + ks * 32 + lg * 8;
        const float* p3 = Wv2 + (size_t)(64 * w + 3 * 16 + ln) * HH + ks * 32 + lg * 8;
        short8v f0, f1, f2, f3;
        #pragma unroll
        for (int j = 0; j < 8; ++j){
            f0[j] = (short)f2bf(p0[j]); f1[j] = (short)f2bf(p1[j]);
            f2[j] = (short)f2bf(p2[j]); f3[j] = (short)f2bf(p3[j]);
        }
        a2f0[ks] = f0; a2f1[ks] = f1; a2f2[ks] = f2; a2f3[ks] = f3;
    }
    if (tid < HH){ bv0L[tid] = bv0[tid]; bv1L[tid] = bv1[tid]; }
    bv2L[tid] = bv2[tid];
    WrL[tid]  = Wr[tid];
    if (tid < OUTD) brL[tid] = br[tid];
    {
        float* sF = &sAll[0][0];
        for (int i = tid; i < 4 * NWIN * DD; i += 512){
            int c = i >> 10;
            sF[i] = s1g[(size_t)(b0 + c) * (NWIN * DD) + (i & 1023)];
        }
        float* bF = &bAll[0][0];
        for (int i = tid; i < 4 * NWIN * PP; i += 512){
            int c = i / (NWIN * PP);
            bF[i] = s2g[(size_t)(b0 + c) * (NWIN * PP) + (i - c * (NWIN * PP))];
        }
    }
    __syncthreads();

    // -------- initial MLP (f32) for 4 chains + Cexp for step 0 --------
    {
        int c4 = tid >> 7, r = tid & 127;
        float acc = bi0[r];
        const float* x0 = x + (size_t)(b0 + c4) * TT * DD;
        #pragma unroll
        for (int k = 0; k < DD; ++k) acc += Wi0[r * DD + k] * x0[k];
        s0p[c4][r] = softplus_f(acc);
    }
    if (tid < 256){
        int cc = tid >> 6, dd = (tid >> 3) & 7, ee = tid & 7;
        const float* bco = &bAll[cc][0];
        float cv = 0.f;
        if (ee < dd)      cv =  bco[((ee * (15 - ee)) >> 1) + dd - ee - 1];
        else if (ee > dd) cv = -bco[((dd * (15 - dd)) >> 1) + ee - dd - 1];
        Cexp[cc][dd][ee] = cv;
    }
    __syncthreads();
    {
        int c4 = tid >> 7, r = tid & 127;
        float acc = bi1[r];
        const f32x4* wv = (const f32x4*)(Wi1 + (size_t)r * HH);
        const f32x4* zv = (const f32x4*)&s0p[c4][0];
        #pragma unroll 8
        for (int k = 0; k < 32; ++k){
            f32x4 a = wv[k], z = zv[k];
            acc += a.x * z.x + a.y * z.y + a.z * z.z + a.w * z.w;
        }
        s1p[c4][r] = softplus_f(acc);
    }
    __syncthreads();
    if (tid < 256){
        int c4 = tid >> 6, s = tid & 63;
        float acc = bi2[s];
        const f32x4* wv = (const f32x4*)(Wi2 + (size_t)s * HH);
        const f32x4* zv = (const f32x4*)&s1p[c4][0];
        #pragma unroll 8
        for (int k = 0; k < 32; ++k){
            f32x4 a = wv[k], z = zv[k];
            acc += a.x * z.x + a.y * z.y + a.z * z.z + a.w * z.w;
        }
        hfb[c4][0][s] = acc;
        BpH[BPOS(s, c4)] = (short)f2bf(acc);
    }
    __syncthreads();

    const f32x4 zero4 = {0.f, 0.f, 0.f, 0.f};
    const int rb = w * 16 + lg * 4;

    // -------- scan --------
    for (int n = 0; n < NWIN; ++n){
        // ---- S1: z0 = sp(W0 @ h), cols 0-3 = 4 chains ----
        {
            f32x4 acc = zero4;
            acc = __builtin_amdgcn_mfma_f32_16x16x32_bf16(a0f[0], *(const short8v*)&BpH[(0 * 64 + l) * 8], acc, 0, 0, 0);
            acc = __builtin_amdgcn_mfma_f32_16x16x32_bf16(a0f[1], *(const short8v*)&BpH[(1 * 64 + l) * 8], acc, 0, 0, 0);
            if (ln < 4){
                int c = ln;
                f32x4 bv = *(const f32x4*)&bv0L[rb];
                float z[4], sgv[4];
                #pragma unroll
                for (int r = 0; r < 4; ++r){
                    float zz, gg;
                    sp_sig(acc[r] + bv[r], zz, gg);
                    z[r] = zz; sgv[r] = gg;
                }
                f32x4 sg = {sgv[0], sgv[1], sgv[2], sgv[3]};
                *(f32x4*)&s0p[c][rb] = sg;
                uint2 pk; pk.x = pk2(z[0], z[1]); pk.y = pk2(z[2], z[3]);
                *(uint2*)&Bp0[BPOS(rb, c)] = pk;
            }
        }
        __syncthreads();

        // ---- S3: z1 = sp(W1 @ z0); chain c -> Bp1 cols 4c..4c+3 (dup) ----
        {
            f32x4 acc = zero4;
            #pragma unroll
            for (int ks = 0; ks < 4; ++ks)
                acc = __builtin_amdgcn_mfma_f32_16x16x32_bf16(a1f[ks], *(const short8v*)&Bp0[(ks * 64 + l) * 8], acc, 0, 0, 0);
            if (ln < 4){
                int c = ln;
                f32x4 bv = *(const f32x4*)&bv1L[rb];
                float z[4], sgv[4];
                #pragma unroll
                for (int r = 0; r < 4; ++r){
                    float zz, gg;
                    sp_sig(acc[r] + bv[r], zz, gg);
                    z[r] = zz; sgv[r] = gg;
                }
                f32x4 sg = {sgv[0], sgv[1], sgv[2], sgv[3]};
                *(f32x4*)&s1p[c][rb] = sg;
                uint2 pk; pk.x = pk2(z[0], z[1]); pk.y = pk2(z[2], z[3]);
                #pragma unroll
                for (int cc = 0; cc < 4; ++cc) *(uint2*)&Bp1[BPOS(rb, c * 4 + cc)] = pk;
            }
        }
        __syncthreads();

        // ---- S4: V_d = tanh(W2_d @ z1 + bv2), d = w; all 16 lanes: c=ln>>2, t=ln&3 ----
        {
            short8v bf[4];
            #pragma unroll
            for (int ks = 0; ks < 4; ++ks) bf[ks] = *(const short8v*)&Bp1[(ks * 64 + l) * 8];
            f32x4 acc0 = zero4, acc1 = zero4, acc2 = zero4, acc3 = zero4;
            #pragma unroll
            for (int ks = 0; ks < 4; ++ks){
                acc0 = __builtin_amdgcn_mfma_f32_16x16x32_bf16(a2f0[ks], bf[ks], acc0, 0, 0, 0);
                acc1 = __builtin_amdgcn_mfma_f32_16x16x32_bf16(a2f1[ks], bf[ks], acc1, 0, 0, 0);
                acc2 = __builtin_amdgcn_mfma_f32_16x16x32_bf16(a2f2[ks], bf[ks], acc2, 0, 0, 0);
                acc3 = __builtin_amdgcn_mfma_f32_16x16x32_bf16(a2f3[ks], bf[ks], acc3, 0, 0, 0);
            }
            {
                int c = ln >> 2, t = ln & 3;
                f32x4 av = (t == 0) ? acc0 : (t == 1) ? acc1 : (t == 2) ? acc2 : acc3;
                int r4 = 64 * w + t * 16 + lg * 4;
                f32x4 bv = *(const f32x4*)&bv2L[r4];
                f32x4 vv;
                #pragma unroll
                for (int r = 0; r < 4; ++r) vv[r] = tanh_f(av[r] + bv[r]);
                *(f32x4*)&Vl[c * 512 + r4] = vv;
                int sl = t * 16 + lg * 4;
                uint2 pk; pk.x = pk2(vv[0], vv[1]); pk.y = pk2(vv[2], vv[3]);
                *(uint2*)&BpV[c >> 1][BPOS(sl, (c & 1) * 8 + w)] = pk;
            }
        }
        __syncthreads();

        // ---- S7: per pair, Y = W0 @ V^T (N=16); bf16-packed col-mix with Cexp ----
        {
            #pragma unroll
            for (int p = 0; p < 2; ++p){
                f32x4 acc = zero4;
                acc = __builtin_amdgcn_mfma_f32_16x16x32_bf16(a0f[0], *(const short8v*)&BpV[p][(0 * 64 + l) * 8], acc, 0, 0, 0);
                acc = __builtin_amdgcn_mfma_f32_16x16x32_bf16(a0f[1], *(const short8v*)&BpV[p][(1 * 64 + l) * 8], acc, 0, 0, 0);
                int c = 2 * p + (ln >> 3), d = ln & 7;
                f32x4 cm0 = *(const f32x4*)&Cexp[c][d][0];
                f32x4 cm1 = *(const f32x4*)&Cexp[c][d][4];
                unsigned pka = pk2(acc[0], acc[1]);
                unsigned pkb = pk2(acc[2], acc[3]);
                float tm0 = 0.f, tm1 = 0.f, tm2 = 0.f, tm3 = 0.f;
                #pragma unroll
                for (int e = 0; e < 8; ++e){
                    float ce = (e < 4) ? cm0[e] : cm1[e - 4];
                    int src = (l & 48) | (ln & 8) | e;
                    unsigned qa = (unsigned)__shfl((int)pka, src);
                    unsigned qb = (unsigned)__shfl((int)pkb, src);
                    tm0 += ce * __builtin_bit_cast(float, qa << 16);
                    tm1 += ce * __builtin_bit_cast(float, qa & 0xffff0000u);
                    tm2 += ce * __builtin_bit_cast(float, qb << 16);
                    tm3 += ce * __builtin_bit_cast(float, qb & 0xffff0000u);
                }
                f32x4 sg = *(const f32x4*)&s0p[c][rb];
                uint2 pk; pk.x = pk2(sg[0] * tm0, sg[1] * tm1); pk.y = pk2(sg[2] * tm2, sg[3] * tm3);
                *(uint2*)&Bp8[p][BPOS(rb, ln)] = pk;
            }
        }
        __syncthreads();

        // ---- S8: per pair, q = s1' * (W1 @ t0) ----
        {
            #pragma unroll
            for (int p = 0; p < 2; ++p){
                f32x4 acc = zero4;
                #pragma unroll
                for (int ks = 0; ks < 4; ++ks)
                    acc = __builtin_amdgcn_mfma_f32_16x16x32_bf16(a1f[ks], *(const short8v*)&Bp8[p][(ks * 64 + l) * 8], acc, 0, 0, 0);
                int c = 2 * p + (ln >> 3);
                f32x4 sg = *(const f32x4*)&s1p[c][rb];
                uint2 pk; pk.x = pk2(sg[0] * acc[0], sg[1] * acc[1]); pk.y = pk2(sg[2] * acc[2], sg[3] * acc[3]);
                *(uint2*)&Bp9[p][BPOS(rb, ln)] = pk;
            }
        }
        __syncthreads();

        // ---- S9: per pair, R_d = (1-V_d^2) * (W2_d @ q[:,c,d]), d = w ----
        {
            #pragma unroll
            for (int p = 0; p < 2; ++p){
                short8v bf[4];
                #pragma unroll
                for (int ks = 0; ks < 4; ++ks) bf[ks] = *(const short8v*)&Bp9[p][(ks * 64 + l) * 8];
                f32x4 acc0 = zero4, acc1 = zero4, acc2 = zero4, acc3 = zero4;
                #pragma unroll
                for (int ks = 0; ks < 4; ++ks){
                    acc0 = __builtin_amdgcn_mfma_f32_16x16x32_bf16(a2f0[ks], bf[ks], acc0, 0, 0, 0);
                    acc1 = __builtin_amdgcn_mfma_f32_16x16x32_bf16(a2f1[ks], bf[ks], acc1, 0, 0, 0);
                    acc2 = __builtin_amdgcn_mfma_f32_16x16x32_bf16(a2f2[ks], bf[ks], acc2, 0, 0, 0);
                    acc3 = __builtin_amdgcn_mfma_f32_16x16x32_bf16(a2f3[ks], bf[ks], acc3, 0, 0, 0);
                }
                if ((ln & 7) == w){
                    int c = 2 * p + (ln >> 3);
                    #pragma unroll
                    for (int t = 0; t < 4; ++t){
                        f32x4 av = (t == 0) ? acc0 : (t == 1) ? acc1 : (t == 2) ? acc2 : acc3;
                        int r4 = 64 * w + t * 16 + lg * 4;
                        f32x4 vv = *(const f32x4*)&Vl[c * 512 + r4];
                        f32x4 rr;
                        #pragma unroll
                        for (int r = 0; r < 4; ++r) rr[r] = (1.f - vv[r] * vv[r]) * av[r];
                        *(f32x4*)&Rf[c * 512 + r4] = rr;
                    }
                }
            }
        }
        __syncthreads();

        // ---- upd: waves 0-3 h-update (c=w) | waves 4-7 readout + Cexp(n+1) + flush ----
        {
            const int cur = n & 1;
            if (w < 4){
                int c = w, s = l;
                float hN = hfb[c][cur][s];
                #pragma unroll
                for (int d = 0; d < DD; ++d)
                    hN += sAll[c][n * DD + d] * Vl[c * 512 + d * 64 + s] + Rf[c * 512 + d * 64 + s];
                hfb[c][cur ^ 1][s] = hN;
                BpH[BPOS(s, c)] = (short)f2bf(hN);
            } else {
                // Cexp for step n+1
                {
                    int idx = (w - 4) * 64 + l;
                    int cc = idx >> 6, dd = (idx >> 3) & 7, ee = idx & 7;
                    int nn = (n + 1 < NWIN) ? n + 1 : NWIN - 1;
                    const float* bco = &bAll[cc][nn * PP];
                    float cv = 0.f;
                    if (ee < dd)      cv =  bco[((ee * (15 - ee)) >> 1) + dd - ee - 1];
                    else if (ee > dd) cv = -bco[((dd * (15 - dd)) >> 1) + ee - dd - 1];
                    Cexp[cc][dd][ee] = cv;
                }
                int c = w - 4;
                int o = l >> 3, qq = l & 7;
                f32x4 w0 = *(const f32x4*)&WrL[o * SS + qq * 8];
                f32x4 w1 = *(const f32x4*)&WrL[o * SS + qq * 8 + 4];
                f32x4 h0 = *(const f32x4*)&hfb[c][cur][qq * 8];
                f32x4 h1 = *(const f32x4*)&hfb[c][cur][qq * 8 + 4];
                float acc = w0.x*h0.x + w0.y*h0.y + w0.z*h0.z + w0.w*h0.w
                          + w1.x*h1.x + w1.y*h1.y + w1.z*h1.z + w1.w*h1.w;
                acc += __shfl_xor(acc, 1); acc += __shfl_xor(acc, 2); acc += __shfl_xor(acc, 4);
                if (qq == 0) outC[c][n & 31][o] = brL[o] + acc;
                if ((n & 31) == 31){
                    size_t base = (size_t)(b0 + c) * (NWIN + 1) * OUTD + (size_t)(n - 31) * OUTD;
                    const f32x4* oc = (const f32x4*)&outC[c][0][0];
                    f32x4 v = oc[l];
                    *(f32x4*)&out[base + l * 4] = v;
                }
            }
        }
        __syncthreads();
    }

    // final readout: h_NWIN in hfb[c][0] (NWIN even)
    if (w >= 4){
        int c = w - 4;
        int o = l >> 3, qq = l & 7;
        f32x4 w0 = *(const f32x4*)&WrL[o * SS + qq * 8];
        f32x4 w1 = *(const f32x4*)&WrL[o * SS + qq * 8 + 4];
        f32x4 h0 = *(const f32x4*)&hfb[c][0][qq * 8];
        f32x4 h1 = *(const f32x4*)&hfb[c][0][qq * 8 + 4];
        float acc = w0.x*h0.x + w0.y*h0.y + w0.z*h0.z + w0.w*h0.w
                  + w1.x*h1.x + w1.y*h1.y + w1.z*h1.z + w1.w*h1.w;
        acc += __shfl_xor(acc, 1); acc += __shfl_xor(acc, 2); acc += __shfl_xor(acc, 4);
        if (qq == 0)
            out[(size_t)(b0 + c) * (NWIN + 1) * OUTD + (size_t)NWIN * OUTD + o] = brL[o] + acc;
    }
}

extern "C" void kernel_launch(void* const* d_in, const int* in_sizes, int n_in,
                              void* d_out, int out_size, void* d_ws, size_t ws_size,
                              hipStream_t stream){
    const float* x   = (const float*)d_in[1];
    const float* Wi0 = (const float*)d_in[2];
    const float* bi0 = (const float*)d_in[3];
    const float* Wi1 = (const float*)d_in[4];
    const float* bi1 = (const float*)d_in[5];
    const float* Wi2 = (const float*)d_in[6];
    const float* bi2 = (const float*)d_in[7];
    const float* Wv0 = (const float*)d_in[8];
    const float* bv0 = (const float*)d_in[9];
    const float* Wv1 = (const float*)d_in[10];
    const float* bv1 = (const float*)d_in[11];
    const float* Wv2 = (const float*)d_in[12];
    const float* bv2 = (const float*)d_in[13];
    const float* Wr  = (const float*)d_in[14];
    const float* br  = (const float*)d_in[15];
    float* out = (float*)d_out;

    float* s1w = (float*)d_ws;
    float* s2w = s1w + (size_t)BB * NWIN * DD;

    sig_kernel<<<(BB * NWIN + 255) / 256, 256, 0, stream>>>(x, s1w, s2w);
    scan_kernel<<<BB / 4, 512, 0, stream>>>(x, Wi0, bi0, Wi1, bi1, Wi2, bi2,
                                            Wv0, bv0, Wv1, bv1, Wv2, bv2,
                                            Wr, br, s1w, s2w, out);
}

// Round 12
// 544.366 us; speedup vs baseline: 4.0585x; 1.2188x over previous
//
#include <hip/hip_runtime.h>
#include <hip/hip_bf16.h>

#define DD 8
#define SS 64
#define HH 128
#define OUTD 8
#define TT 2049
#define BB 32
#define WINW 16
#define NWIN 128
#define PP 28

typedef __attribute__((ext_vector_type(8))) short short8v;
typedef __attribute__((ext_vector_type(4))) float f32x4;

__device__ __forceinline__ float softplus_f(float x){
    return fmaxf(x, 0.f) + __logf(1.f + __expf(-fabsf(x)));
}
__device__ __forceinline__ float tanh_f(float x){
    float e = __expf(2.f * x);
    return 1.f - 2.f / (e + 1.f);
}
// fused softplus + sigmoid sharing t = exp(-|x|)
__device__ __forceinline__ void sp_sig(float x, float& sp, float& sg){
    float t = __expf(-fabsf(x));
    float r = 1.f / (1.f + t);
    sg = x > 0.f ? r : 1.f - r;
    sp = fmaxf(x, 0.f) - __logf(r);
}
__device__ __forceinline__ unsigned short f2bf(float f){
    return __builtin_bit_cast(unsigned short, __float2bfloat16(f));
}
__device__ __forceinline__ unsigned pk2(float a, float b){
    unsigned lo = (unsigned)__builtin_bit_cast(unsigned short, __float2bfloat16(a));
    unsigned hi = (unsigned)__builtin_bit_cast(unsigned short, __float2bfloat16(b));
    return lo | (hi << 16);
}

// ---------------- signatures: s1 (B,NWIN,D), s2 (B,NWIN,P) ----------------
__global__ void sig_kernel(const float* __restrict__ x,
                           float* __restrict__ s1o, float* __restrict__ s2o){
    int w = blockIdx.x * blockDim.x + threadIdx.x;
    if (w >= BB * NWIN) return;
    int b = w >> 7, n = w & (NWIN - 1);
    const float* xp = x + ((size_t)b * TT + (size_t)n * WINW) * DD;
    float prev[DD], cum[DD], s1v[DD], M[DD][DD];
    #pragma unroll
    for (int i = 0; i < DD; ++i){
        cum[i] = 0.f; s1v[i] = 0.f;
        #pragma unroll
        for (int j = 0; j < DD; ++j) M[i][j] = 0.f;
    }
    #pragma unroll
    for (int i = 0; i < DD; ++i) prev[i] = xp[i];
    for (int t = 0; t < WINW; ++t){
        float cur[DD], del[DD];
        #pragma unroll
        for (int i = 0; i < DD; ++i) cur[i] = xp[(t + 1) * DD + i];
        #pragma unroll
        for (int i = 0; i < DD; ++i) del[i] = cur[i] - prev[i];
        #pragma unroll
        for (int i = 0; i < DD; ++i){
            #pragma unroll
            for (int j = 0; j < DD; ++j) M[i][j] += cum[i] * del[j];
        }
        #pragma unroll
        for (int i = 0; i < DD; ++i){ cum[i] += del[i]; s1v[i] += del[i]; prev[i] = cur[i]; }
    }
    #pragma unroll
    for (int i = 0; i < DD; ++i) s1o[(size_t)w * DD + i] = s1v[i];
    int p = 0;
    #pragma unroll
    for (int i = 0; i < DD; ++i){
        #pragma unroll
        for (int j = i + 1; j < DD; ++j){ s2o[(size_t)w * PP + p] = 0.5f * (M[i][j] - M[j][i]); ++p; }
    }
}

// image position (shorts): k-row k, col nn of a [K/32][64][8] B-image
#define BPOS(k, nn) ((((k) >> 5) * 64 + (((k) >> 3) & 3) * 16 + (nn)) * 8 + ((k) & 7))

// ---------------- main scan: 4 chains per 512-thread block, 8 waves ----------------
__global__ __launch_bounds__(512, 2) void scan_kernel(
    const float* __restrict__ x,
    const float* __restrict__ Wi0, const float* __restrict__ bi0,
    const float* __restrict__ Wi1, const float* __restrict__ bi1,
    const float* __restrict__ Wi2, const float* __restrict__ bi2,
    const float* __restrict__ Wv0, const float* __restrict__ bv0,
    const float* __restrict__ Wv1, const float* __restrict__ bv1,
    const float* __restrict__ Wv2, const float* __restrict__ bv2,
    const float* __restrict__ Wr,  const float* __restrict__ br,
    const float* __restrict__ s1g, const float* __restrict__ s2g,
    float* __restrict__ out)
{
    const int tid = threadIdx.x;
    const int w   = tid >> 6;   // wave 0..7 (= m-tile / d-block)
    const int l   = tid & 63;
    const int lg  = l >> 4;
    const int ln  = l & 15;
    const int b0  = blockIdx.x * 4;

    __shared__ __align__(16) short BpH[2 * 64 * 8];       // h:  cols 0-3 = chains
    __shared__ __align__(16) short Bp0[4 * 64 * 8];       // z0: cols 0-3
    __shared__ __align__(16) short Bp1[4 * 64 * 8];       // z1: chain c -> cols 4c..4c+3 (dup)
    __shared__ __align__(16) short Bp7[2][2 * 64 * 8];    // u:  image c>>1, col (c&1)*8+d
    __shared__ __align__(16) short Bp8[2][4 * 64 * 8];    // t0: image p,    col (c&1)*8+d (c=2p+..)
    __shared__ __align__(16) short Bp9[2][4 * 64 * 8];    // q:  image d>>2, col (d&3)*4+c
    __shared__ __align__(16) float s0p[4][HH], s1p[4][HH];
    __shared__ __align__(16) float Vl[4 * 512], Rf[4 * 512];
    __shared__ __align__(16) float hfb[4][2][SS];
    __shared__ __align__(16) float bv0L[HH], bv1L[HH], bv2L[512];
    __shared__ __align__(16) float WrL[OUTD * SS];
    __shared__ float brL[OUTD];
    __shared__ __align__(16) float sAll[4][NWIN * DD];    // 16 KB
    __shared__ __align__(16) float bAll[4][NWIN * PP];    // 56 KB
    __shared__ __align__(16) float outC[4][32][OUTD];     // 4 KB output chunk
    __shared__ __align__(16) float Cexp[4][DD][12];       // expanded C, padded rows (48B)

    // -------- prologue: reg A-fragments, stage weights + coefficients --------
    short8v a0f[2], a1f[4];
    short8v a2f0[4], a2f1[4], a2f2[4], a2f3[4];
    #pragma unroll
    for (int ks = 0; ks < 2; ++ks){
        const float* p = Wv0 + (size_t)(w * 16 + ln) * SS + ks * 32 + lg * 8;
        short8v f;
        #pragma unroll
        for (int j = 0; j < 8; ++j) f[j] = (short)f2bf(p[j]);
        a0f[ks] = f;
    }
    #pragma unroll
    for (int ks = 0; ks < 4; ++ks){
        const float* p = Wv1 + (size_t)(w * 16 + ln) * HH + ks * 32 + lg * 8;
        short8v f;
        #pragma unroll
        for (int j = 0; j < 8; ++j) f[j] = (short)f2bf(p[j]);
        a1f[ks] = f;
    }
    #pragma unroll
    for (int ks = 0; ks < 4; ++ks){
        const float* p0 = Wv2 + (size_t)(64 * w + 0 * 16 + ln) * HH + ks * 32 + lg * 8;
        const float* p1 = Wv2 + (size_t)(64 * w + 1 * 16 + ln) * HH + ks * 32 + lg * 8;
        const float* p2 = Wv2 + (size_t)(64 * w + 2 * 16 + ln) * HH + ks * 32 + lg * 8;
        const float* p3 = Wv2 + (size_t)(64 * w + 3 * 16 + ln) * HH + ks * 32 + lg * 8;
        short8v f0, f1, f2, f3;
        #pragma unroll
        for (int j = 0; j < 8; ++j){
            f0[j] = (short)f2bf(p0[j]); f1[j] = (short)f2bf(p1[j]);
            f2[j] = (short)f2bf(p2[j]); f3[j] = (short)f2bf(p3[j]);
        }
        a2f0[ks] = f0; a2f1[ks] = f1; a2f2[ks] = f2; a2f3[ks] = f3;
    }
    if (tid < HH){ bv0L[tid] = bv0[tid]; bv1L[tid] = bv1[tid]; }
    bv2L[tid] = bv2[tid];
    WrL[tid]  = Wr[tid];
    if (tid < OUTD) brL[tid] = br[tid];
    {
        float* sF = &sAll[0][0];
        for (int i = tid; i < 4 * NWIN * DD; i += 512){
            int c = i >> 10;
            sF[i] = s1g[(size_t)(b0 + c) * (NWIN * DD) + (i & 1023)];
        }
        float* bF = &bAll[0][0];
        for (int i = tid; i < 4 * NWIN * PP; i += 512){
            int c = i / (NWIN * PP);
            bF[i] = s2g[(size_t)(b0 + c) * (NWIN * PP) + (i - c * (NWIN * PP))];
        }
        // zero pad columns of GEMV images once
        for (int i = tid; i < 2 * 64 * 8; i += 512) BpH[i] = 0;
        for (int i = tid; i < 4 * 64 * 8; i += 512){ Bp0[i] = 0; Bp1[i] = 0; }
    }
    __syncthreads();

    // -------- initial MLP (f32) for 4 chains + Cexp for step 0 --------
    {
        int c4 = tid >> 7, r = tid & 127;
        float acc = bi0[r];
        const float* x0 = x + (size_t)(b0 + c4) * TT * DD;
        #pragma unroll
        for (int k = 0; k < DD; ++k) acc += Wi0[r * DD + k] * x0[k];
        s0p[c4][r] = softplus_f(acc);
    }
    if (tid < 256){
        int cc = tid >> 6, dd = (tid >> 3) & 7, ee = tid & 7;
        const float* bco = &bAll[cc][0];
        float cv = 0.f;
        if (ee < dd)      cv =  bco[((ee * (15 - ee)) >> 1) + dd - ee - 1];
        else if (ee > dd) cv = -bco[((dd * (15 - dd)) >> 1) + ee - dd - 1];
        Cexp[cc][dd][ee] = cv;
    }
    __syncthreads();
    {
        int c4 = tid >> 7, r = tid & 127;
        float acc = bi1[r];
        const f32x4* wv = (const f32x4*)(Wi1 + (size_t)r * HH);
        const f32x4* zv = (const f32x4*)&s0p[c4][0];
        #pragma unroll 8
        for (int k = 0; k < 32; ++k){
            f32x4 a = wv[k], z = zv[k];
            acc += a.x * z.x + a.y * z.y + a.z * z.z + a.w * z.w;
        }
        s1p[c4][r] = softplus_f(acc);
    }
    __syncthreads();
    if (tid < 256){
        int c4 = tid >> 6, s = tid & 63;
        float acc = bi2[s];
        const f32x4* wv = (const f32x4*)(Wi2 + (size_t)s * HH);
        const f32x4* zv = (const f32x4*)&s1p[c4][0];
        #pragma unroll 8
        for (int k = 0; k < 32; ++k){
            f32x4 a = wv[k], z = zv[k];
            acc += a.x * z.x + a.y * z.y + a.z * z.z + a.w * z.w;
        }
        hfb[c4][0][s] = acc;
        BpH[BPOS(s, c4)] = (short)f2bf(acc);
    }
    __syncthreads();

    const f32x4 zero4 = {0.f, 0.f, 0.f, 0.f};
    const int rb = w * 16 + lg * 4;

    // -------- scan --------
    for (int n = 0; n < NWIN; ++n){
        // ---- S1: z0 = sp(W0 @ h), cols 0-3 = 4 chains ----
        {
            f32x4 acc = zero4;
            acc = __builtin_amdgcn_mfma_f32_16x16x32_bf16(a0f[0], *(const short8v*)&BpH[(0 * 64 + l) * 8], acc, 0, 0, 0);
            acc = __builtin_amdgcn_mfma_f32_16x16x32_bf16(a0f[1], *(const short8v*)&BpH[(1 * 64 + l) * 8], acc, 0, 0, 0);
            if (ln < 4){
                int c = ln;
                f32x4 bv = *(const f32x4*)&bv0L[rb];
                float z[4], sgv[4];
                #pragma unroll
                for (int r = 0; r < 4; ++r){
                    float zz, gg;
                    sp_sig(acc[r] + bv[r], zz, gg);
                    z[r] = zz; sgv[r] = gg;
                }
                f32x4 sg = {sgv[0], sgv[1], sgv[2], sgv[3]};
                *(f32x4*)&s0p[c][rb] = sg;
                uint2 pk; pk.x = pk2(z[0], z[1]); pk.y = pk2(z[2], z[3]);
                *(uint2*)&Bp0[BPOS(rb, c)] = pk;
            }
        }
        __syncthreads();

        // ---- S3: z1 = sp(W1 @ z0); chain c -> Bp1 cols 4c..4c+3 (dup) ----
        {
            f32x4 acc = zero4;
            #pragma unroll
            for (int ks = 0; ks < 4; ++ks)
                acc = __builtin_amdgcn_mfma_f32_16x16x32_bf16(a1f[ks], *(const short8v*)&Bp0[(ks * 64 + l) * 8], acc, 0, 0, 0);
            if (ln < 4){
                int c = ln;
                f32x4 bv = *(const f32x4*)&bv1L[rb];
                float z[4], sgv[4];
                #pragma unroll
                for (int r = 0; r < 4; ++r){
                    float zz, gg;
                    sp_sig(acc[r] + bv[r], zz, gg);
                    z[r] = zz; sgv[r] = gg;
                }
                f32x4 sg = {sgv[0], sgv[1], sgv[2], sgv[3]};
                *(f32x4*)&s1p[c][rb] = sg;
                uint2 pk; pk.x = pk2(z[0], z[1]); pk.y = pk2(z[2], z[3]);
                #pragma unroll
                for (int cc = 0; cc < 4; ++cc) *(uint2*)&Bp1[BPOS(rb, c * 4 + cc)] = pk;
            }
        }
        __syncthreads();

        // ---- S4: V_d = tanh(W2_d @ z1 + bv2), d = w; lanes: c=ln>>2, t=ln&3 ----
        {
            short8v bf[4];
            #pragma unroll
            for (int ks = 0; ks < 4; ++ks) bf[ks] = *(const short8v*)&Bp1[(ks * 64 + l) * 8];
            f32x4 acc0 = zero4, acc1 = zero4, acc2 = zero4, acc3 = zero4;
            #pragma unroll
            for (int ks = 0; ks < 4; ++ks){
                acc0 = __builtin_amdgcn_mfma_f32_16x16x32_bf16(a2f0[ks], bf[ks], acc0, 0, 0, 0);
                acc1 = __builtin_amdgcn_mfma_f32_16x16x32_bf16(a2f1[ks], bf[ks], acc1, 0, 0, 0);
                acc2 = __builtin_amdgcn_mfma_f32_16x16x32_bf16(a2f2[ks], bf[ks], acc2, 0, 0, 0);
                acc3 = __builtin_amdgcn_mfma_f32_16x16x32_bf16(a2f3[ks], bf[ks], acc3, 0, 0, 0);
            }
            {
                int c = ln >> 2, t = ln & 3;
                f32x4 av = (t == 0) ? acc0 : (t == 1) ? acc1 : (t == 2) ? acc2 : acc3;
                int r4 = 64 * w + t * 16 + lg * 4;
                f32x4 bv = *(const f32x4*)&bv2L[r4];
                f32x4 vv;
                #pragma unroll
                for (int r = 0; r < 4; ++r) vv[r] = tanh_f(av[r] + bv[r]);
                *(f32x4*)&Vl[c * 512 + r4] = vv;
            }
        }
        __syncthreads();

        // ---- U: u[c][d] = sum_e Cexp[c][d][e] * V[c][e]; 512 thr, 4 s each ----
        {
            int c = tid >> 7, d = (tid >> 4) & 7, s0v = (tid & 15) * 4;
            f32x4 cm0 = *(const f32x4*)&Cexp[c][d][0];
            f32x4 cm1 = *(const f32x4*)&Cexp[c][d][4];
            f32x4 acc = zero4;
            #pragma unroll
            for (int e = 0; e < 8; ++e){
                float ce = (e < 4) ? cm0[e] : cm1[e - 4];
                f32x4 v4 = *(const f32x4*)&Vl[c * 512 + e * 64 + s0v];
                acc.x += ce * v4.x; acc.y += ce * v4.y;
                acc.z += ce * v4.z; acc.w += ce * v4.w;
            }
            uint2 pk; pk.x = pk2(acc.x, acc.y); pk.y = pk2(acc.z, acc.w);
            *(uint2*)&Bp7[c >> 1][BPOS(s0v, (c & 1) * 8 + d)] = pk;
        }
        __syncthreads();

        // ---- S7: t0 = s0' * (W0 @ u); all 16 cols; write Bp8 (same col) ----
        {
            #pragma unroll
            for (int p = 0; p < 2; ++p){
                f32x4 acc = zero4;
                acc = __builtin_amdgcn_mfma_f32_16x16x32_bf16(a0f[0], *(const short8v*)&Bp7[p][(0 * 64 + l) * 8], acc, 0, 0, 0);
                acc = __builtin_amdgcn_mfma_f32_16x16x32_bf16(a0f[1], *(const short8v*)&Bp7[p][(1 * 64 + l) * 8], acc, 0, 0, 0);
                int c = 2 * p + (ln >> 3);
                f32x4 sg = *(const f32x4*)&s0p[c][rb];
                uint2 pk; pk.x = pk2(sg[0] * acc[0], sg[1] * acc[1]);
                pk.y = pk2(sg[2] * acc[2], sg[3] * acc[3]);
                *(uint2*)&Bp8[p][BPOS(rb, ln)] = pk;
            }
        }
        __syncthreads();

        // ---- S8: q = s1' * (W1 @ t0); write Bp9 relabeled: img d>>2, col (d&3)*4+c ----
        {
            #pragma unroll
            for (int p = 0; p < 2; ++p){
                f32x4 acc = zero4;
                #pragma unroll
                for (int ks = 0; ks < 4; ++ks)
                    acc = __builtin_amdgcn_mfma_f32_16x16x32_bf16(a1f[ks], *(const short8v*)&Bp8[p][(ks * 64 + l) * 8], acc, 0, 0, 0);
                int c = 2 * p + (ln >> 3), d = ln & 7;
                f32x4 sg = *(const f32x4*)&s1p[c][rb];
                uint2 pk; pk.x = pk2(sg[0] * acc[0], sg[1] * acc[1]);
                pk.y = pk2(sg[2] * acc[2], sg[3] * acc[3]);
                *(uint2*)&Bp9[d >> 2][BPOS(rb, (d & 3) * 4 + c)] = pk;
            }
        }
        __syncthreads();

        // ---- S9: R_d = (1-V^2) * (W2_d @ q[:,c,d]), d = w; ONE image (w>>2) ----
        {
            const int im = w >> 2;
            short8v bf[4];
            #pragma unroll
            for (int ks = 0; ks < 4; ++ks) bf[ks] = *(const short8v*)&Bp9[im][(ks * 64 + l) * 8];
            f32x4 acc0 = zero4, acc1 = zero4, acc2 = zero4, acc3 = zero4;
            #pragma unroll
            for (int ks = 0; ks < 4; ++ks){
                acc0 = __builtin_amdgcn_mfma_f32_16x16x32_bf16(a2f0[ks], bf[ks], acc0, 0, 0, 0);
                acc1 = __builtin_amdgcn_mfma_f32_16x16x32_bf16(a2f1[ks], bf[ks], acc1, 0, 0, 0);
                acc2 = __builtin_amdgcn_mfma_f32_16x16x32_bf16(a2f2[ks], bf[ks], acc2, 0, 0, 0);
                acc3 = __builtin_amdgcn_mfma_f32_16x16x32_bf16(a2f3[ks], bf[ks], acc3, 0, 0, 0);
            }
            if ((ln >> 2) == (w & 3)){
                int c = ln & 3;
                #pragma unroll
                for (int t = 0; t < 4; ++t){
                    f32x4 av = (t == 0) ? acc0 : (t == 1) ? acc1 : (t == 2) ? acc2 : acc3;
                    int r4 = 64 * w + t * 16 + lg * 4;
                    f32x4 vv = *(const f32x4*)&Vl[c * 512 + r4];
                    f32x4 rr;
                    #pragma unroll
                    for (int r = 0; r < 4; ++r) rr[r] = (1.f - vv[r] * vv[r]) * av[r];
                    *(f32x4*)&Rf[c * 512 + r4] = rr;
                }
            }
        }
        __syncthreads();

        // ---- upd: waves 0-3 h-update (c=w) | waves 4-7 readout + Cexp(n+1) + flush ----
        {
            const int cur = n & 1;
            if (w < 4){
                int c = w, s = l;
                f32x4 a0 = *(const f32x4*)&sAll[c][n * DD];
                f32x4 a1 = *(const f32x4*)&sAll[c][n * DD + 4];
                float hN = hfb[c][cur][s];
                #pragma unroll
                for (int d = 0; d < 4; ++d)
                    hN += a0[d] * Vl[c * 512 + d * 64 + s] + Rf[c * 512 + d * 64 + s];
                #pragma unroll
                for (int d = 4; d < 8; ++d)
                    hN += a1[d - 4] * Vl[c * 512 + d * 64 + s] + Rf[c * 512 + d * 64 + s];
                hfb[c][cur ^ 1][s] = hN;
                BpH[BPOS(s, c)] = (short)f2bf(hN);
            } else {
                // Cexp for step n+1
                {
                    int idx = (w - 4) * 64 + l;
                    int cc = idx >> 6, dd = (idx >> 3) & 7, ee = idx & 7;
                    int nn = (n + 1 < NWIN) ? n + 1 : NWIN - 1;
                    const float* bco = &bAll[cc][nn * PP];
                    float cv = 0.f;
                    if (ee < dd)      cv =  bco[((ee * (15 - ee)) >> 1) + dd - ee - 1];
                    else if (ee > dd) cv = -bco[((dd * (15 - dd)) >> 1) + ee - dd - 1];
                    Cexp[cc][dd][ee] = cv;
                }
                int c = w - 4;
                int o = l >> 3, qq = l & 7;
                f32x4 w0 = *(const f32x4*)&WrL[o * SS + qq * 8];
                f32x4 w1 = *(const f32x4*)&WrL[o * SS + qq * 8 + 4];
                f32x4 h0 = *(const f32x4*)&hfb[c][cur][qq * 8];
                f32x4 h1 = *(const f32x4*)&hfb[c][cur][qq * 8 + 4];
                float acc = w0.x*h0.x + w0.y*h0.y + w0.z*h0.z + w0.w*h0.w
                          + w1.x*h1.x + w1.y*h1.y + w1.z*h1.z + w1.w*h1.w;
                acc += __shfl_xor(acc, 1); acc += __shfl_xor(acc, 2); acc += __shfl_xor(acc, 4);
                if (qq == 0) outC[c][n & 31][o] = brL[o] + acc;
                if ((n & 31) == 31){
                    size_t base = (size_t)(b0 + c) * (NWIN + 1) * OUTD + (size_t)(n - 31) * OUTD;
                    const f32x4* oc = (const f32x4*)&outC[c][0][0];
                    f32x4 v = oc[l];
                    *(f32x4*)&out[base + l * 4] = v;
                }
            }
        }
        __syncthreads();
    }

    // final readout: h_NWIN in hfb[c][0] (NWIN even)
    if (w >= 4){
        int c = w - 4;
        int o = l >> 3, qq = l & 7;
        f32x4 w0 = *(const f32x4*)&WrL[o * SS + qq * 8];
        f32x4 w1 = *(const f32x4*)&WrL[o * SS + qq * 8 + 4];
        f32x4 h0 = *(const f32x4*)&hfb[c][0][qq * 8];
        f32x4 h1 = *(const f32x4*)&hfb[c][0][qq * 8 + 4];
        float acc = w0.x*h0.x + w0.y*h0.y + w0.z*h0.z + w0.w*h0.w
                  + w1.x*h1.x + w1.y*h1.y + w1.z*h1.z + w1.w*h1.w;
        acc += __shfl_xor(acc, 1); acc += __shfl_xor(acc, 2); acc += __shfl_xor(acc, 4);
        if (qq == 0)
            out[(size_t)(b0 + c) * (NWIN + 1) * OUTD + (size_t)NWIN * OUTD + o] = brL[o] + acc;
    }
}

extern "C" void kernel_launch(void* const* d_in, const int* in_sizes, int n_in,
                              void* d_out, int out_size, void* d_ws, size_t ws_size,
                              hipStream_t stream){
    const float* x   = (const float*)d_in[1];
    const float* Wi0 = (const float*)d_in[2];
    const float* bi0 = (const float*)d_in[3];
    const float* Wi1 = (const float*)d_in[4];
    const float* bi1 = (const float*)d_in[5];
    const float* Wi2 = (const float*)d_in[6];
    const float* bi2 = (const float*)d_in[7];
    const float* Wv0 = (const float*)d_in[8];
    const float* bv0 = (const float*)d_in[9];
    const float* Wv1 = (const float*)d_in[10];
    const float* bv1 = (const float*)d_in[11];
    const float* Wv2 = (const float*)d_in[12];
    const float* bv2 = (const float*)d_in[13];
    const float* Wr  = (const float*)d_in[14];
    const float* br  = (const float*)d_in[15];
    float* out = (float*)d_out;

    float* s1w = (float*)d_ws;
    float* s2w = s1w + (size_t)BB * NWIN * DD;

    sig_kernel<<<(BB * NWIN + 255) / 256, 256, 0, stream>>>(x, s1w, s2w);
    scan_kernel<<<BB / 4, 512, 0, stream>>>(x, Wi0, bi0, Wi1, bi1, Wi2, bi2,
                                            Wv0, bv0, Wv1, bv1, Wv2, bv2,
                                            Wr, br, s1w, s2w, out);
}